// Round 9
// baseline (200.665 us; speedup 1.0000x reference)
//
#include <hip/hip_runtime.h>
#include <stdint.h>
#include <math.h>

// ---------------------------------------------------------------------------
// SubsetItems, round 9: INSTRUMENTATION ROUND on the r7 structure (19.5us).
// Outputs bit-identical (absmax 0.0 r1-r8). Each kernel's core compute is
// looped R times with a zz*rep perturbation (zz=0 at runtime) so LICM/CSE
// can't collapse reps and asm keep-alives stop DCE. Purpose: push our three
// kernels past the harness's 39us ws-poison fills so the top-5 rocprof table
// finally shows per-kernel dur/VALUBusy/Occupancy/timestamps (boundary gaps).
//   noise    R=32   rank-search R=32   finalize-sum R=64
// ---------------------------------------------------------------------------

#define RANK_G 64
#define JCHUNK 64
#define IPT    16

#define R_NOISE 32
#define R_RANK  32
#define R_FIN   64

struct TF2 { uint32_t a, b; };

__host__ __device__ inline TF2 threefry2x32(uint32_t k0, uint32_t k1,
                                            uint32_t x0, uint32_t x1) {
  const uint32_t ks2 = k0 ^ k1 ^ 0x1BD11BDAu;
#define TF_ROT(v, d) (uint32_t)(((v) << (d)) | ((v) >> (32 - (d))))
#define TF_RND(r) do { x0 += x1; x1 = TF_ROT(x1, r); x1 ^= x0; } while (0)
  x0 += k0; x1 += k1;
  TF_RND(13); TF_RND(15); TF_RND(26); TF_RND(6);
  x0 += k1; x1 += ks2 + 1u;
  TF_RND(17); TF_RND(29); TF_RND(16); TF_RND(24);
  x0 += ks2; x1 += k0 + 2u;
  TF_RND(13); TF_RND(15); TF_RND(26); TF_RND(6);
  x0 += k0; x1 += k1 + 3u;
  TF_RND(17); TF_RND(29); TF_RND(16); TF_RND(24);
  x0 += k1; x1 += ks2 + 4u;
  TF_RND(13); TF_RND(15); TF_RND(26); TF_RND(6);
  x0 += ks2; x1 += k0 + 5u;
#undef TF_RND
#undef TF_ROT
  return {x0, x1};
}

__host__ __device__ __forceinline__ uint32_t random_bits_at(uint32_t ka, uint32_t kb,
                                                            uint32_t idx) {
  TF2 r = threefry2x32(ka, kb, 0u, idx);
  return r.a ^ r.b;
}

// XLA/CHLO ErfInv f32 (bit-exact, verified r1-r8).
__device__ __forceinline__ float erfinv_f32_xla(float x) {
  float xx = __fmul_rn(x, x);
  float v  = -xx;
  float w;
  if (fabsf(v) < 1e-4f) {
    float t = __fmul_rn(__fadd_rn(__fmul_rn(-0.5f, v), 1.0f), v);
    w = -t;
  } else {
    float t = __fadd_rn(v, 1.0f);
    w = -(float)log((double)t);
  }
  float p;
  if (w < 5.0f) {
    float ww = __fadd_rn(w, -2.5f);
    p = 2.81022636e-08f;
    p = __fadd_rn( 3.43273939e-07f, __fmul_rn(p, ww));
    p = __fadd_rn(-3.5233877e-06f,  __fmul_rn(p, ww));
    p = __fadd_rn(-4.39150654e-06f, __fmul_rn(p, ww));
    p = __fadd_rn( 0.00021858087f,  __fmul_rn(p, ww));
    p = __fadd_rn(-0.00125372503f,  __fmul_rn(p, ww));
    p = __fadd_rn(-0.00417768164f,  __fmul_rn(p, ww));
    p = __fadd_rn( 0.246640727f,    __fmul_rn(p, ww));
    p = __fadd_rn( 1.50140941f,     __fmul_rn(p, ww));
  } else {
    float ww = __fadd_rn(__fsqrt_rn(w), -3.0f);
    p = -0.000200214257f;
    p = __fadd_rn( 0.000100950558f, __fmul_rn(p, ww));
    p = __fadd_rn( 0.00134934322f,  __fmul_rn(p, ww));
    p = __fadd_rn(-0.00367342844f,  __fmul_rn(p, ww));
    p = __fadd_rn( 0.00573950773f,  __fmul_rn(p, ww));
    p = __fadd_rn(-0.0076224613f,   __fmul_rn(p, ww));
    p = __fadd_rn( 0.00943887047f,  __fmul_rn(p, ww));
    p = __fadd_rn( 1.00167406f,     __fmul_rn(p, ww));
    p = __fadd_rn( 2.83297682f,     __fmul_rn(p, ww));
  }
  return __fmul_rn(p, x);
}

// Kernel 1: x_noised -> packed 64-bit total-order key. Core looped R_NOISE x.
__global__ __launch_bounds__(256)
void noise_kernel(const float* __restrict__ scores, uint64_t* __restrict__ k64,
                  uint32_t k1a, uint32_t k1b, uint32_t k3a, uint32_t k3b,
                  uint32_t rowmask, uint32_t zz) {
  int e = blockIdx.x * 256 + threadIdx.x;   // 32768
  int b = e >> 12;

  float s  = scores[e];
  float sf = scores[32767 - e];

  float xnv = 0.0f;
  for (int rep = 0; rep < R_NOISE; ++rep) {
    uint32_t pert = zz * (uint32_t)rep;     // == 0 at runtime

    uint32_t mbits = random_bits_at(k1a ^ pert, k1b, (uint32_t)e);
    bool mask = ((mbits >> 9) <= 838860u) && ((rowmask >> b) & 1u);

    float v  = mask ? fmaxf(s, sf) : s;
    float x  = fminf(fmaxf(v, -1.0f), 1.0f);

    uint32_t nbits = random_bits_at(k3a ^ pert, k3b, (uint32_t)e);
    float f   = __uint_as_float((nbits >> 9) | 0x3f800000u);
    float f01 = __fadd_rn(f, -1.0f);
    const float lo = __uint_as_float(0xBF7FFFFFu);
    float u = __fadd_rn(__fmul_rn(f01, 2.0f), lo);
    u = fmaxf(lo, u);
    float p    = erfinv_f32_xla(u);
    float nrm  = __fmul_rn(__uint_as_float(0x3FB504F3u), p);
    float nois = __fmul_rn(nrm, 0.0009765625f);
    xnv = __fadd_rn(x, nois);
    asm volatile("" :: "v"(xnv));           // keep each rep live
  }

  uint32_t ub = __float_as_uint(xnv);
  uint32_t tk = (ub & 0x80000000u) ? ~ub : (ub | 0x80000000u);
  k64[e] = ((uint64_t)tk << 32) | (uint32_t)(e & 4095);
}

// Kernel 2: sort once, step-major lower_bound looped R_RANK x.
__global__ __launch_bounds__(256)
void rank_kernel(const uint64_t* __restrict__ k64,
                 uint32_t* __restrict__ partial, uint32_t zz) {
  __shared__ uint64_t jraw[JCHUNK];
  __shared__ uint64_t jsrt[JCHUNK];
  int row = blockIdx.x >> 6;              // /RANK_G
  int g   = blockIdx.x & (RANK_G - 1);
  const uint64_t* rk = k64 + row * 4096;
  int t = threadIdx.x;

  uint64_t ki[IPT];
#pragma unroll
  for (int m = 0; m < IPT; ++m) ki[m] = rk[m * 256 + t];

  if (t < JCHUNK) jraw[t] = rk[g * JCHUNK + t];
  __syncthreads();
  if (t < JCHUNK) {
    uint64_t kt = jraw[t];
    int r = 0;
#pragma unroll 8
    for (int u = 0; u < JCHUNK; ++u) r += (int)(jraw[u] < kt);
    jsrt[r] = kt;
  }
  __syncthreads();

  const int offs[7] = {31, 15, 7, 3, 1, 0, 0};
  const int incs[7] = {32, 16, 8, 4, 2, 1, 1};

  int pos[IPT];
  for (int rep = 0; rep < R_RANK; ++rep) {
    uint64_t pert = (uint64_t)(zz * (uint32_t)rep);   // == 0 at runtime
#pragma unroll
    for (int m = 0; m < IPT; ++m) pos[m] = 0;
#pragma unroll
    for (int s = 0; s < 7; ++s) {
      uint64_t v[IPT];
#pragma unroll
      for (int m = 0; m < IPT; ++m) v[m] = jsrt[pos[m] + offs[s]];
#pragma unroll
      for (int m = 0; m < IPT; ++m)
        pos[m] += (v[m] < (ki[m] | pert)) ? incs[s] : 0;
    }
#pragma unroll
    for (int m = 0; m < IPT; ++m) asm volatile("" :: "v"(pos[m]));
  }

  uint32_t* pw = partial + (row * RANK_G + g) * 1024;
#pragma unroll
  for (int q = 0; q < 4; ++q) {
    uint32_t w = (uint32_t)pos[4 * q]
               | ((uint32_t)pos[4 * q + 1] << 8)
               | ((uint32_t)pos[4 * q + 2] << 16)
               | ((uint32_t)pos[4 * q + 3] << 24);
    pw[q * 256 + t] = w;
  }
}

// Kernel 3: partial-sum looped R_FIN x (rep 0 cold, reps 1+ L2-hot).
__global__ __launch_bounds__(256)
void finalize_kernel(const uint32_t* __restrict__ partial,
                     float* __restrict__ out, uint32_t zz) {
  int row = blockIdx.x >> 2;
  int q   = blockIdx.x & 3;
  int t   = threadIdx.x;
  const uint32_t* prow = partial + row * RANK_G * 1024 + q * 256 + t;

  int acc0 = 0, acc1 = 0, acc2 = 0, acc3 = 0;
  for (int rep = 0; rep < R_FIN; ++rep) {
    const uint32_t* p2 = prow + (size_t)(zz * (uint32_t)rep);  // == prow
    acc0 = 0; acc1 = 0; acc2 = 0; acc3 = 0;
#pragma unroll 16
    for (int g = 0; g < RANK_G; ++g) {
      uint32_t w = p2[g * 1024];
      acc0 += (int)(w & 0xFFu);
      acc1 += (int)((w >> 8) & 0xFFu);
      acc2 += (int)((w >> 16) & 0xFFu);
      acc3 += (int)((w >> 24) & 0xFFu);
    }
    asm volatile("" :: "v"(acc0), "v"(acc1), "v"(acc2), "v"(acc3));
  }

  int accs[4] = {acc0, acc1, acc2, acc3};
#pragma unroll
  for (int b = 0; b < 4; ++b) {
    int r = accs[b];
    if (r >= 2048) {
      int j = r - 2048;
      int i = (4 * q + b) * 256 + t;
      out[row * 2048 + j] = (float)i;
      out[16384 + row * 2048 + j] = fminf(__fdiv_rn((float)j, 204.8f), 1.0f);
    }
  }
}

extern "C" void kernel_launch(void* const* d_in, const int* in_sizes, int n_in,
                              void* d_out, int out_size, void* d_ws, size_t ws_size,
                              hipStream_t stream) {
  const float* scores = (const float*)d_in[0];
  float* out = (float*)d_out;

  uint64_t* k64     = (uint64_t*)d_ws;                          // 256 KB
  uint32_t* partial = (uint32_t*)((uint8_t*)d_ws + 32768 * 8);  // 2 MB

  TF2 K1 = threefry2x32(0u, 42u, 0u, 0u);
  TF2 K2 = threefry2x32(0u, 42u, 0u, 1u);
  TF2 K3 = threefry2x32(0u, 42u, 0u, 2u);

  uint32_t rowmask = 0;
  for (uint32_t b = 0; b < 8; ++b) {
    uint32_t bits = random_bits_at(K2.a, K2.b, b);
    if ((bits >> 9) < 6291456u) rowmask |= (1u << b);
  }

  const uint32_t zz = 0u;   // runtime zero; defeats LICM/CSE in rep loops

  noise_kernel<<<128, 256, 0, stream>>>(scores, k64,
                                        K1.a, K1.b, K3.a, K3.b, rowmask, zz);
  rank_kernel<<<8 * RANK_G, 256, 0, stream>>>(k64, partial, zz);
  finalize_kernel<<<32, 256, 0, stream>>>(partial, out, zz);
}

// Round 10
// 22.285 us; speedup vs baseline: 9.0045x; 9.0045x over previous
//
#include <hip/hip_runtime.h>
#include <stdint.h>
#include <math.h>

// ---------------------------------------------------------------------------
// SubsetItems, round 10: bit-exact math (absmax 0.0 r1-r9). 3 dispatches.
// Change vs r7 (19.5us best): finalize rebuilt wave-per-column (r9 showed it
// latency-bound at 32 blocks, ~1.8us/rep L2-hot): lane l reads partial[row]
// [g=l][k], u64 16-bit-field expand, 6x shfl_xor reduce, lane0 scatters.
// 2048 blocks -> 8192 waves, latency hidden by TLP.
//   k1 noise    -> packed 64-bit total-order keys (tk<<32 | col)
//   k2 rank     -> per-block j-chunk sort + step-major lower_bound, u8x4 pack
//   k3 finalize -> wave-per-column shfl reduction, scatter idx+weight
// ---------------------------------------------------------------------------

#define RANK_G 64
#define JCHUNK 64
#define IPT    16

struct TF2 { uint32_t a, b; };

__host__ __device__ inline TF2 threefry2x32(uint32_t k0, uint32_t k1,
                                            uint32_t x0, uint32_t x1) {
  const uint32_t ks2 = k0 ^ k1 ^ 0x1BD11BDAu;
#define TF_ROT(v, d) (uint32_t)(((v) << (d)) | ((v) >> (32 - (d))))
#define TF_RND(r) do { x0 += x1; x1 = TF_ROT(x1, r); x1 ^= x0; } while (0)
  x0 += k0; x1 += k1;
  TF_RND(13); TF_RND(15); TF_RND(26); TF_RND(6);
  x0 += k1; x1 += ks2 + 1u;
  TF_RND(17); TF_RND(29); TF_RND(16); TF_RND(24);
  x0 += ks2; x1 += k0 + 2u;
  TF_RND(13); TF_RND(15); TF_RND(26); TF_RND(6);
  x0 += k0; x1 += k1 + 3u;
  TF_RND(17); TF_RND(29); TF_RND(16); TF_RND(24);
  x0 += k1; x1 += ks2 + 4u;
  TF_RND(13); TF_RND(15); TF_RND(26); TF_RND(6);
  x0 += ks2; x1 += k0 + 5u;
#undef TF_RND
#undef TF_ROT
  return {x0, x1};
}

__host__ __device__ __forceinline__ uint32_t random_bits_at(uint32_t ka, uint32_t kb,
                                                            uint32_t idx) {
  TF2 r = threefry2x32(ka, kb, 0u, idx);
  return r.a ^ r.b;
}

// XLA/CHLO ErfInv f32 (bit-exact, verified r1-r9).
__device__ __forceinline__ float erfinv_f32_xla(float x) {
  float xx = __fmul_rn(x, x);
  float v  = -xx;
  float w;
  if (fabsf(v) < 1e-4f) {
    float t = __fmul_rn(__fadd_rn(__fmul_rn(-0.5f, v), 1.0f), v);
    w = -t;
  } else {
    float t = __fadd_rn(v, 1.0f);
    w = -(float)log((double)t);
  }
  float p;
  if (w < 5.0f) {
    float ww = __fadd_rn(w, -2.5f);
    p = 2.81022636e-08f;
    p = __fadd_rn( 3.43273939e-07f, __fmul_rn(p, ww));
    p = __fadd_rn(-3.5233877e-06f,  __fmul_rn(p, ww));
    p = __fadd_rn(-4.39150654e-06f, __fmul_rn(p, ww));
    p = __fadd_rn( 0.00021858087f,  __fmul_rn(p, ww));
    p = __fadd_rn(-0.00125372503f,  __fmul_rn(p, ww));
    p = __fadd_rn(-0.00417768164f,  __fmul_rn(p, ww));
    p = __fadd_rn( 0.246640727f,    __fmul_rn(p, ww));
    p = __fadd_rn( 1.50140941f,     __fmul_rn(p, ww));
  } else {
    float ww = __fadd_rn(__fsqrt_rn(w), -3.0f);
    p = -0.000200214257f;
    p = __fadd_rn( 0.000100950558f, __fmul_rn(p, ww));
    p = __fadd_rn( 0.00134934322f,  __fmul_rn(p, ww));
    p = __fadd_rn(-0.00367342844f,  __fmul_rn(p, ww));
    p = __fadd_rn( 0.00573950773f,  __fmul_rn(p, ww));
    p = __fadd_rn(-0.0076224613f,   __fmul_rn(p, ww));
    p = __fadd_rn( 0.00943887047f,  __fmul_rn(p, ww));
    p = __fadd_rn( 1.00167406f,     __fmul_rn(p, ww));
    p = __fadd_rn( 2.83297682f,     __fmul_rn(p, ww));
  }
  return __fmul_rn(p, x);
}

// Kernel 1: x_noised -> packed 64-bit total-order key.
__global__ __launch_bounds__(256)
void noise_kernel(const float* __restrict__ scores, uint64_t* __restrict__ k64,
                  uint32_t k1a, uint32_t k1b, uint32_t k3a, uint32_t k3b,
                  uint32_t rowmask) {
  int e = blockIdx.x * 256 + threadIdx.x;   // 32768
  int b = e >> 12;

  uint32_t mbits = random_bits_at(k1a, k1b, (uint32_t)e);
  bool mask = ((mbits >> 9) <= 838860u) && ((rowmask >> b) & 1u);

  float s  = scores[e];
  float sf = scores[32767 - e];
  float v  = mask ? fmaxf(s, sf) : s;
  float x  = fminf(fmaxf(v, -1.0f), 1.0f);

  uint32_t nbits = random_bits_at(k3a, k3b, (uint32_t)e);
  float f   = __uint_as_float((nbits >> 9) | 0x3f800000u);
  float f01 = __fadd_rn(f, -1.0f);
  const float lo = __uint_as_float(0xBF7FFFFFu);
  float u = __fadd_rn(__fmul_rn(f01, 2.0f), lo);
  u = fmaxf(lo, u);
  float p    = erfinv_f32_xla(u);
  float nrm  = __fmul_rn(__uint_as_float(0x3FB504F3u), p);
  float nois = __fmul_rn(nrm, 0.0009765625f);
  float xnv  = __fadd_rn(x, nois);

  uint32_t ub = __float_as_uint(xnv);
  uint32_t tk = (ub & 0x80000000u) ? ~ub : (ub | 0x80000000u);
  k64[e] = ((uint64_t)tk << 32) | (uint32_t)(e & 4095);
}

// Kernel 2: partial ranks via per-block j-chunk sort + STEP-MAJOR lower_bound.
// partial word (row,g,q,t) packs counts of i = (4q+b)*256+t in byte b.
__global__ __launch_bounds__(256)
void rank_kernel(const uint64_t* __restrict__ k64,
                 uint32_t* __restrict__ partial) {
  __shared__ uint64_t jraw[JCHUNK];
  __shared__ uint64_t jsrt[JCHUNK];
  int row = blockIdx.x >> 6;              // /RANK_G
  int g   = blockIdx.x & (RANK_G - 1);
  const uint64_t* rk = k64 + row * 4096;
  int t = threadIdx.x;

  // i-keys (independent global loads overlap the sort)
  uint64_t ki[IPT];
#pragma unroll
  for (int m = 0; m < IPT; ++m) ki[m] = rk[m * 256 + t];

  if (t < JCHUNK) jraw[t] = rk[g * JCHUNK + t];
  __syncthreads();
  if (t < JCHUNK) {
    uint64_t kt = jraw[t];
    int r = 0;
#pragma unroll 8
    for (int u = 0; u < JCHUNK; ++u) r += (int)(jraw[u] < kt);
    jsrt[r] = kt;                         // keys unique -> exact ranks
  }
  __syncthreads();

  // step-major branchless lower_bound: pos[m] = #{j in chunk : key_j < ki[m]}
  int pos[IPT];
#pragma unroll
  for (int m = 0; m < IPT; ++m) pos[m] = 0;

  const int offs[7] = {31, 15, 7, 3, 1, 0, 0};
  const int incs[7] = {32, 16, 8, 4, 2, 1, 1};
#pragma unroll
  for (int s = 0; s < 7; ++s) {
    uint64_t v[IPT];
#pragma unroll
    for (int m = 0; m < IPT; ++m) v[m] = jsrt[pos[m] + offs[s]];
#pragma unroll
    for (int m = 0; m < IPT; ++m) pos[m] += (v[m] < ki[m]) ? incs[s] : 0;
  }

  uint32_t* pw = partial + (row * RANK_G + g) * 1024;
#pragma unroll
  for (int q = 0; q < 4; ++q) {
    uint32_t w = (uint32_t)pos[4 * q]
               | ((uint32_t)pos[4 * q + 1] << 8)
               | ((uint32_t)pos[4 * q + 2] << 16)
               | ((uint32_t)pos[4 * q + 3] << 24);
    pw[q * 256 + t] = w;
  }
}

// Kernel 3: wave-per-column reduction. Column c=(row,k); lane l reads the
// packed word [row][g=l][k]; bytes expand to u64 16-bit fields (max 4096,
// no carry); 6x shfl_xor u64 reduce; lane 0 scatters <=4 outputs.
__global__ __launch_bounds__(256)
void finalize_kernel(const uint32_t* __restrict__ partial,
                     float* __restrict__ out) {
  int wave = threadIdx.x >> 6;            // 0..3
  int lane = threadIdx.x & 63;
  int c    = blockIdx.x * 4 + wave;       // 0..8191
  int row  = c >> 10;
  int k    = c & 1023;

  uint32_t w = partial[(row * RANK_G + lane) * 1024 + k];
  unsigned long long e =  (unsigned long long)(w & 0xFFu)
                       | ((unsigned long long)((w >> 8)  & 0xFFu) << 16)
                       | ((unsigned long long)((w >> 16) & 0xFFu) << 32)
                       | ((unsigned long long)((w >> 24) & 0xFFu) << 48);
#pragma unroll
  for (int d = 32; d >= 1; d >>= 1) e += __shfl_xor(e, d, 64);

  if (lane == 0) {
    int q = k >> 8, tt = k & 255;
#pragma unroll
    for (int b = 0; b < 4; ++b) {
      int r = (int)((e >> (16 * b)) & 0xFFFFull);
      if (r >= 2048) {
        int j = r - 2048;
        int i = (4 * q + b) * 256 + tt;
        out[row * 2048 + j] = (float)i;
        out[16384 + row * 2048 + j] = fminf(__fdiv_rn((float)j, 204.8f), 1.0f);
      }
    }
  }
}

extern "C" void kernel_launch(void* const* d_in, const int* in_sizes, int n_in,
                              void* d_out, int out_size, void* d_ws, size_t ws_size,
                              hipStream_t stream) {
  const float* scores = (const float*)d_in[0];
  float* out = (float*)d_out;

  uint64_t* k64     = (uint64_t*)d_ws;                          // 256 KB
  uint32_t* partial = (uint32_t*)((uint8_t*)d_ws + 32768 * 8);  // 2 MB

  // split(key(42), 3), partitionable layout (verified r1)
  TF2 K1 = threefry2x32(0u, 42u, 0u, 0u);
  TF2 K2 = threefry2x32(0u, 42u, 0u, 1u);
  TF2 K3 = threefry2x32(0u, 42u, 0u, 2u);

  // batch_mask rows on host: uniform(k2,(8,1)) < 0.75
  uint32_t rowmask = 0;
  for (uint32_t b = 0; b < 8; ++b) {
    uint32_t bits = random_bits_at(K2.a, K2.b, b);
    if ((bits >> 9) < 6291456u) rowmask |= (1u << b);
  }

  noise_kernel<<<128, 256, 0, stream>>>(scores, k64,
                                        K1.a, K1.b, K3.a, K3.b, rowmask);
  rank_kernel<<<8 * RANK_G, 256, 0, stream>>>(k64, partial);
  finalize_kernel<<<2048, 256, 0, stream>>>(partial, out);
}